// Round 1
// baseline (287.791 us; speedup 1.0000x reference)
//
#include <hip/hip_runtime.h>
#include <hip/hip_bf16.h>
#include <cstdint>

#define FEAT    128
#define NRBF    20
#define NATOMS  8192
#define NEDGES  262144
#define NGRAPH  128
#define APG     64
#define PI_F    3.14159265358979323846f
#define CUTOFF_F 5.0f

// ---------------------------------------------------------------- GEMM (K=128)
// C[M x N] = act(A[M x 128] @ W[128 x N] + b), tile 64x64, block 256, 4x4/thread
__global__ __launch_bounds__(256) void gemm_k128(
    const float* __restrict__ A, const float* __restrict__ W,
    const float* __restrict__ bias, float* __restrict__ C,
    int N, int act_silu) {
  __shared__ float As[64][132];
  __shared__ float Ws[128][68];
  const int r0 = blockIdx.x * 64;
  const int c0 = blockIdx.y * 64;
  const int t = threadIdx.x;

  // load A tile (64 x 128) as float4
  {
    const float* Abase = A + (size_t)r0 * 128;
    for (int i = t; i < 64 * 32; i += 256) {
      int r = i >> 5, k4 = i & 31;
      float4 v = *reinterpret_cast<const float4*>(Abase + r * 128 + k4 * 4);
      *reinterpret_cast<float4*>(&As[r][k4 * 4]) = v;
    }
  }
  // load W tile (128 x 64) as float4
  {
    for (int i = t; i < 128 * 16; i += 256) {
      int k = i >> 4, c4 = i & 15;
      float4 v = *reinterpret_cast<const float4*>(W + (size_t)k * N + c0 + c4 * 4);
      *reinterpret_cast<float4*>(&Ws[k][c4 * 4]) = v;
    }
  }
  __syncthreads();

  const int tx = t & 15, ty = t >> 4;
  float acc[4][4] = {};
  #pragma unroll 4
  for (int k4 = 0; k4 < 32; ++k4) {
    float4 a0 = *reinterpret_cast<const float4*>(&As[ty * 4 + 0][4 * k4]);
    float4 a1 = *reinterpret_cast<const float4*>(&As[ty * 4 + 1][4 * k4]);
    float4 a2 = *reinterpret_cast<const float4*>(&As[ty * 4 + 2][4 * k4]);
    float4 a3 = *reinterpret_cast<const float4*>(&As[ty * 4 + 3][4 * k4]);
    float4 w0 = *reinterpret_cast<const float4*>(&Ws[4 * k4 + 0][tx * 4]);
    float4 w1 = *reinterpret_cast<const float4*>(&Ws[4 * k4 + 1][tx * 4]);
    float4 w2 = *reinterpret_cast<const float4*>(&Ws[4 * k4 + 2][tx * 4]);
    float4 w3 = *reinterpret_cast<const float4*>(&Ws[4 * k4 + 3][tx * 4]);
    #define UPD(i, av)                                              \
      acc[i][0] += av.x*w0.x + av.y*w1.x + av.z*w2.x + av.w*w3.x;   \
      acc[i][1] += av.x*w0.y + av.y*w1.y + av.z*w2.y + av.w*w3.y;   \
      acc[i][2] += av.x*w0.z + av.y*w1.z + av.z*w2.z + av.w*w3.z;   \
      acc[i][3] += av.x*w0.w + av.y*w1.w + av.z*w2.w + av.w*w3.w;
    UPD(0, a0) UPD(1, a1) UPD(2, a2) UPD(3, a3)
    #undef UPD
  }

  float4 bb = *reinterpret_cast<const float4*>(bias + c0 + tx * 4);
  #pragma unroll
  for (int i = 0; i < 4; ++i) {
    float o0 = acc[i][0] + bb.x;
    float o1 = acc[i][1] + bb.y;
    float o2 = acc[i][2] + bb.z;
    float o3 = acc[i][3] + bb.w;
    if (act_silu) {
      o0 = o0 / (1.f + __expf(-o0));
      o1 = o1 / (1.f + __expf(-o1));
      o2 = o2 / (1.f + __expf(-o2));
      o3 = o3 / (1.f + __expf(-o3));
    }
    float4 ov = {o0, o1, o2, o3};
    *reinterpret_cast<float4*>(C + (size_t)(r0 + ty * 4 + i) * N + c0 + tx * 4) = ov;
  }
}

// ---------------------------------------------------------------- sort helpers
__global__ void zero_kernel(int* __restrict__ p, int n) {
  int i = blockIdx.x * blockDim.x + threadIdx.x;
  if (i < n) p[i] = 0;
}

__global__ void hist_kernel(const int* __restrict__ nbrs, int* __restrict__ counts) {
  int e = blockIdx.x * blockDim.x + threadIdx.x;
  if (e < NEDGES) atomicAdd(&counts[nbrs[2 * e]], 1);
}

__global__ __launch_bounds__(1024) void scan_kernel(
    const int* __restrict__ counts, int* __restrict__ offs, int* __restrict__ cursor) {
  __shared__ int part[1024];
  const int t = threadIdx.x;
  int local[8];
  int s = 0;
  #pragma unroll
  for (int i = 0; i < 8; ++i) { local[i] = counts[t * 8 + i]; s += local[i]; }
  part[t] = s;
  __syncthreads();
  for (int off = 1; off < 1024; off <<= 1) {
    int v = part[t];
    int add = (t >= off) ? part[t - off] : 0;
    __syncthreads();
    part[t] = v + add;
    __syncthreads();
  }
  int excl = part[t] - s;
  #pragma unroll
  for (int i = 0; i < 8; ++i) {
    offs[t * 8 + i] = excl;
    cursor[t * 8 + i] = excl;
    excl += local[i];
  }
  if (t == 1023) offs[NATOMS] = excl;
}

__global__ void scatter_kernel(const int* __restrict__ nbrs, int* __restrict__ cursor,
                               int* __restrict__ sorted) {
  int e = blockIdx.x * blockDim.x + threadIdx.x;
  if (e < NEDGES) {
    int seg = nbrs[2 * e];
    int pos = atomicAdd(&cursor[seg], 1);
    sorted[pos] = e;
  }
}

// ---------------------------------------------------------------- edge accumulation
// One wave (64 lanes) per destination atom; lane l owns features {2l, 2l+1}.
// Chunks of 6 edges: RBF*env computed once/edge into LDS, Wr staged in LDS
// as [3][NRBF][128] so float2 reads are dense (conflict-free) and amortized
// over the 6 edges of the chunk.
#define ECH 6
__global__ __launch_bounds__(256) void edge_accum_kernel(
    const int* __restrict__ sorted, const int* __restrict__ offs,
    const int* __restrict__ nbrs, const float* __restrict__ r_ij,
    const float* __restrict__ phi, const float* __restrict__ v_j,
    const float* __restrict__ Wr, const float* __restrict__ br,
    float* __restrict__ out_s, float* __restrict__ out_v) {
  __shared__ float sWr[3 * NRBF * 128];
  __shared__ float eR[4][ECH][NRBF];
  __shared__ float eU[4][ECH][3];
  __shared__ float eE[4][ECH];
  __shared__ int   eJ[4][ECH];

  const int t = threadIdx.x;
  // stage Wr -> [b][n][f]
  for (int i = t; i < 3 * NRBF * 128; i += 256) {
    int f = i & 127;
    int bn = i >> 7;
    int bb = bn / NRBF;
    int n = bn - bb * NRBF;
    sWr[i] = Wr[n * 384 + bb * 128 + f];
  }
  __syncthreads();

  const int w = t >> 6;
  const int l = t & 63;
  const int atom = blockIdx.x * 4 + w;
  const int start = offs[atom];
  const int end = offs[atom + 1];

  float2 br0 = *reinterpret_cast<const float2*>(br + 2 * l);
  float2 br1 = *reinterpret_cast<const float2*>(br + 128 + 2 * l);
  float2 br2 = *reinterpret_cast<const float2*>(br + 256 + 2 * l);

  float ds0 = 0.f, ds1 = 0.f;
  float dv00 = 0.f, dv01 = 0.f, dv02 = 0.f;
  float dv10 = 0.f, dv11 = 0.f, dv12 = 0.f;

  const float c1 = PI_F / CUTOFF_F;

  for (int base = start; base < end; base += ECH) {
    __threadfence_block();  // WAR: previous chunk reads done before overwrite
    // setup: tasks (edge, rbf-index), 120 tasks over 64 lanes (2 rounds)
    #pragma unroll
    for (int rr = 0; rr < 2; ++rr) {
      int task = l + rr * 64;
      if (task < ECH * NRBF) {
        int el = task / NRBF;
        int n = task - el * NRBF;
        int eidx = base + el;
        float rbfv = 0.f;
        if (eidx < end) {
          int e = sorted[eidx];
          float x = r_ij[3 * e], y = r_ij[3 * e + 1], z = r_ij[3 * e + 2];
          float d = sqrtf(x * x + y * y + z * z);
          float env = 0.f;
          if (d < CUTOFF_F) env = 0.5f * (__cosf(c1 * d) + 1.f);
          float inv = 1.f / d;
          rbfv = __sinf((float)(n + 1) * c1 * d) * inv * env;
          if (n == 0) {
            eJ[w][el] = nbrs[2 * e + 1];
            eE[w][el] = env;
            eU[w][el][0] = x * inv;
            eU[w][el][1] = y * inv;
            eU[w][el][2] = z * inv;
          }
        } else if (n == 0) {
          eJ[w][el] = 0;
          eE[w][el] = 0.f;
          eU[w][el][0] = 0.f; eU[w][el][1] = 0.f; eU[w][el][2] = 0.f;
        }
        eR[w][el][n] = rbfv;
      }
    }
    __threadfence_block();  // make setup writes visible before reads

    // w_s for 6 edges, features {2l,2l+1} x 3 blocks
    float wsv[ECH][6];
    #pragma unroll
    for (int el = 0; el < ECH; ++el) {
      float ev = eE[w][el];
      wsv[el][0] = ev * br0.x; wsv[el][1] = ev * br0.y;
      wsv[el][2] = ev * br1.x; wsv[el][3] = ev * br1.y;
      wsv[el][4] = ev * br2.x; wsv[el][5] = ev * br2.y;
    }
    #pragma unroll
    for (int n = 0; n < NRBF; ++n) {
      float2 w0 = *reinterpret_cast<const float2*>(&sWr[(0 * NRBF + n) * 128 + 2 * l]);
      float2 w1 = *reinterpret_cast<const float2*>(&sWr[(1 * NRBF + n) * 128 + 2 * l]);
      float2 w2 = *reinterpret_cast<const float2*>(&sWr[(2 * NRBF + n) * 128 + 2 * l]);
      #pragma unroll
      for (int el = 0; el < ECH; ++el) {
        float rn = eR[w][el][n];
        wsv[el][0] += rn * w0.x; wsv[el][1] += rn * w0.y;
        wsv[el][2] += rn * w1.x; wsv[el][3] += rn * w1.y;
        wsv[el][4] += rn * w2.x; wsv[el][5] += rn * w2.y;
      }
    }
    // per-edge epilogue: gather phi/v rows, accumulate
    #pragma unroll
    for (int el = 0; el < ECH; ++el) {
      int j = eJ[w][el];
      float u0 = eU[w][el][0], u1 = eU[w][el][1], u2 = eU[w][el][2];
      const float* pj = phi + (size_t)j * 384 + 2 * l;
      float2 p0 = *reinterpret_cast<const float2*>(pj);
      float2 p1 = *reinterpret_cast<const float2*>(pj + 128);
      float2 p2 = *reinterpret_cast<const float2*>(pj + 256);
      const float* vj = v_j + (size_t)j * 384 + 6 * l;
      float2 va = *reinterpret_cast<const float2*>(vj);
      float2 vb = *reinterpret_cast<const float2*>(vj + 2);
      float2 vc = *reinterpret_cast<const float2*>(vj + 4);
      float s00 = p0.x * wsv[el][0], s01 = p0.y * wsv[el][1];
      float s10 = p1.x * wsv[el][2], s11 = p1.y * wsv[el][3];
      float s20 = p2.x * wsv[el][4], s21 = p2.y * wsv[el][5];
      ds0 += s10; ds1 += s11;
      dv00 += s20 * u0 + s00 * va.x;
      dv01 += s20 * u1 + s00 * va.y;
      dv02 += s20 * u2 + s00 * vb.x;
      dv10 += s21 * u0 + s01 * vb.y;
      dv11 += s21 * u1 + s01 * vc.x;
      dv12 += s21 * u2 + s01 * vc.y;
    }
  }

  *reinterpret_cast<float2*>(out_s + (size_t)atom * FEAT + 2 * l) = make_float2(ds0, ds1);
  float* ov = out_v + (size_t)atom * 384 + 6 * l;
  *reinterpret_cast<float2*>(ov)     = make_float2(dv00, dv01);
  *reinterpret_cast<float2*>(ov + 2) = make_float2(dv02, dv10);
  *reinterpret_cast<float2*>(ov + 4) = make_float2(dv11, dv12);
}

// ---------------------------------------------------------------- attention
__device__ __forceinline__ float wave_max64(float v) {
  #pragma unroll
  for (int m = 32; m > 0; m >>= 1) v = fmaxf(v, __shfl_xor(v, m, 64));
  return v;
}
__device__ __forceinline__ float wave_sum64(float v) {
  #pragma unroll
  for (int m = 32; m > 0; m >>= 1) v += __shfl_xor(v, m, 64);
  return v;
}

__global__ __launch_bounds__(256) void attn_kernel(const float* __restrict__ qkv,
                                                   float* __restrict__ out_s) {
  __shared__ float4 Ks4[64 * 32];     // XOR-swizzled so lane-strided b128 reads are dense
  __shared__ float  Vs[64][130];
  __shared__ float  Ps[4][4][64];
  const int b = blockIdx.x;
  const int t = threadIdx.x;
  const float* base = qkv + (size_t)b * APG * 384;

  for (int i = t; i < 64 * 32; i += 256) {
    int a = i >> 5, g = i & 31;
    float4 kv = *reinterpret_cast<const float4*>(base + a * 384 + 128 + 4 * g);
    Ks4[a * 32 + (g ^ (a & 7))] = kv;
  }
  for (int i = t; i < 64 * 32; i += 256) {
    int a = i >> 5, g = i & 31;
    float4 vv = *reinterpret_cast<const float4*>(base + a * 384 + 256 + 4 * g);
    Vs[a][4 * g + 0] = vv.x; Vs[a][4 * g + 1] = vv.y;
    Vs[a][4 * g + 2] = vv.z; Vs[a][4 * g + 3] = vv.w;
  }
  __syncthreads();

  const int w = t >> 6, l = t & 63;
  const float scale = 0.08838834764831845f;  // 1/sqrt(128)

  for (int qq = w; qq < 16; qq += 4) {
    const float* q0p = base + (size_t)(4 * qq + 0) * 384;
    const float* q1p = base + (size_t)(4 * qq + 1) * 384;
    const float* q2p = base + (size_t)(4 * qq + 2) * 384;
    const float* q3p = base + (size_t)(4 * qq + 3) * 384;
    float s0 = 0.f, s1 = 0.f, s2 = 0.f, s3 = 0.f;
    #pragma unroll 8
    for (int i = 0; i < 32; ++i) {
      float4 k = Ks4[l * 32 + (i ^ (l & 7))];
      float4 q0 = *reinterpret_cast<const float4*>(q0p + 4 * i);
      float4 q1 = *reinterpret_cast<const float4*>(q1p + 4 * i);
      float4 q2 = *reinterpret_cast<const float4*>(q2p + 4 * i);
      float4 q3 = *reinterpret_cast<const float4*>(q3p + 4 * i);
      s0 += q0.x * k.x + q0.y * k.y + q0.z * k.z + q0.w * k.w;
      s1 += q1.x * k.x + q1.y * k.y + q1.z * k.z + q1.w * k.w;
      s2 += q2.x * k.x + q2.y * k.y + q2.z * k.z + q2.w * k.w;
      s3 += q3.x * k.x + q3.y * k.y + q3.z * k.z + q3.w * k.w;
    }
    s0 *= scale; s1 *= scale; s2 *= scale; s3 *= scale;

    float p0 = __expf(s0 - wave_max64(s0));
    float p1 = __expf(s1 - wave_max64(s1));
    float p2 = __expf(s2 - wave_max64(s2));
    float p3 = __expf(s3 - wave_max64(s3));
    p0 /= wave_sum64(p0); p1 /= wave_sum64(p1);
    p2 /= wave_sum64(p2); p3 /= wave_sum64(p3);

    Ps[w][0][l] = p0; Ps[w][1][l] = p1; Ps[w][2][l] = p2; Ps[w][3][l] = p3;
    __threadfence_block();

    float a00 = 0.f, a01 = 0.f, a10 = 0.f, a11 = 0.f;
    float a20 = 0.f, a21 = 0.f, a30 = 0.f, a31 = 0.f;
    for (int a = 0; a < 64; ++a) {
      float2 v = *reinterpret_cast<const float2*>(&Vs[a][2 * l]);
      float pa0 = Ps[w][0][a], pa1 = Ps[w][1][a];
      float pa2 = Ps[w][2][a], pa3 = Ps[w][3][a];
      a00 += pa0 * v.x; a01 += pa0 * v.y;
      a10 += pa1 * v.x; a11 += pa1 * v.y;
      a20 += pa2 * v.x; a21 += pa2 * v.y;
      a30 += pa3 * v.x; a31 += pa3 * v.y;
    }
    size_t row0 = (size_t)(b * APG + 4 * qq) * FEAT + 2 * l;
    float2* o0 = reinterpret_cast<float2*>(out_s + row0);
    float2* o1 = reinterpret_cast<float2*>(out_s + row0 + FEAT);
    float2* o2 = reinterpret_cast<float2*>(out_s + row0 + 2 * FEAT);
    float2* o3 = reinterpret_cast<float2*>(out_s + row0 + 3 * FEAT);
    float2 c0 = *o0; c0.x += a00; c0.y += a01; *o0 = c0;
    float2 c1 = *o1; c1.x += a10; c1.y += a11; *o1 = c1;
    float2 c2 = *o2; c2.x += a20; c2.y += a21; *o2 = c2;
    float2 c3 = *o3; c3.x += a30; c3.y += a31; *o3 = c3;
    __threadfence_block();  // Ps reads done before next quad overwrites
  }
}

// ---------------------------------------------------------------- launch
extern "C" void kernel_launch(void* const* d_in, const int* in_sizes, int n_in,
                              void* d_out, int out_size, void* d_ws, size_t ws_size,
                              hipStream_t stream) {
  const float* s_j  = (const float*)d_in[0];
  const float* v_j  = (const float*)d_in[1];
  const float* r_ij = (const float*)d_in[2];
  const int*   nbrs = (const int*)d_in[3];
  const float* W1   = (const float*)d_in[5];
  const float* b1   = (const float*)d_in[6];
  const float* W2   = (const float*)d_in[7];
  const float* b2   = (const float*)d_in[8];
  const float* Wr   = (const float*)d_in[9];
  const float* br   = (const float*)d_in[10];
  const float* Wd   = (const float*)d_in[11];
  const float* bd   = (const float*)d_in[12];

  float* out_s = (float*)d_out;
  float* out_v = out_s + (size_t)NATOMS * FEAT;

  float* phi   = (float*)d_ws;                       // 8192*384
  float* qkvb  = phi + (size_t)NATOMS * 384;         // 8192*384 (h aliases its head)
  float* h     = qkvb;                               // 8192*128, dead before qkv write
  int* sorted  = (int*)(qkvb + (size_t)NATOMS * 384);
  int* offs    = sorted + NEDGES;                    // NATOMS+1
  int* cursor  = offs + (NATOMS + 1);
  int* counts  = cursor + NATOMS;

  zero_kernel<<<(NATOMS + 255) / 256, 256, 0, stream>>>(counts, NATOMS);
  gemm_k128<<<dim3(NATOMS / 64, 2), 256, 0, stream>>>(s_j, W1, b1, h, 128, 1);
  gemm_k128<<<dim3(NATOMS / 64, 6), 256, 0, stream>>>(h, W2, b2, phi, 384, 0);
  gemm_k128<<<dim3(NATOMS / 64, 6), 256, 0, stream>>>(s_j, Wd, bd, qkvb, 384, 0);
  hist_kernel<<<NEDGES / 256, 256, 0, stream>>>(nbrs, counts);
  scan_kernel<<<1, 1024, 0, stream>>>(counts, offs, cursor);
  scatter_kernel<<<NEDGES / 256, 256, 0, stream>>>(nbrs, cursor, sorted);
  edge_accum_kernel<<<NATOMS / 4, 256, 0, stream>>>(sorted, offs, nbrs, r_ij, phi,
                                                    v_j, Wr, br, out_s, out_v);
  attn_kernel<<<NGRAPH, 256, 0, stream>>>(qkvb, out_s);
}